// Round 11
// baseline (230.181 us; speedup 1.0000x reference)
//
#include <hip/hip_runtime.h>

#define LOG2E 1.44269504f
#define C_QSCALE 0.360673760f   // 0.25 * log2(e)
#define C_SHIFT  34.6246810f    // 24 * log2(e)
typedef unsigned short u16;
typedef short bf16x8 __attribute__((ext_vector_type(8)));
typedef float f32x4 __attribute__((ext_vector_type(4)));
typedef unsigned short u16x4 __attribute__((ext_vector_type(4)));
typedef unsigned int u32x4 __attribute__((ext_vector_type(4)));

#define BB 2
#define LL 2048
#define HH 1024
#define NH 16
#define HD 64
#define ML (BB*LL)   // 4096 rows total

__device__ __forceinline__ u16 f2bf(float f) {   // round-to-nearest-even
  union { float f; unsigned u; } v; v.f = f;
  unsigned r = v.u + 0x7FFFu + ((v.u >> 16) & 1u);
  return (u16)(r >> 16);
}
__device__ __forceinline__ float bf2f(u16 u) {
  union { unsigned u; float f; } v; v.u = ((unsigned)u) << 16;
  return v.f;
}
__device__ __forceinline__ void gload_lds16(const u16* g, u16* l) {
  __builtin_amdgcn_global_load_lds((const __attribute__((address_space(1))) void*)g,
                                   (__attribute__((address_space(3))) void*)l, 16, 0, 0);
}
// raw hardware exp2 (v_exp_f32): skips the OCML denormal-range fixup (~15 VALU
// instrs/call -> 1). Underflow flushes toward 0, correct for fixed-shift softmax.
__device__ __forceinline__ float fast_exp2(float x) {
  float r; asm("v_exp_f32 %0, %1" : "=v"(r) : "v"(x)); return r;
}
// pack two f32 -> one dword of 2 bf16 (src0 in low half), RNE
__device__ __forceinline__ unsigned cvt_pk_bf16(float lo, float hi) {
  unsigned r;
  asm("v_cvt_pk_bf16_f32 %0, %1, %2" : "=v"(r) : "v"(lo), "v"(hi));
  return r;
}
// a_new = {a.r0, b.r0, a.r2, b.r2}; b_new = {a.r1, b.r1, a.r3, b.r3}  (16-lane rows)
__device__ __forceinline__ void pl16swap(unsigned &a, unsigned &b) {
  asm("v_permlane16_swap_b32 %0, %1" : "+v"(a), "+v"(b));
}
// a_new = {a.lo32, b.lo32}; b_new = {a.hi32, b.hi32}
__device__ __forceinline__ void pl32swap(unsigned &a, unsigned &b) {
  asm("v_permlane32_swap_b32 %0, %1" : "+v"(a), "+v"(b));
}

// ---------------- merged: E fp32->bf16 convert  +  W transpose->bf16 ----------------
__global__ __launch_bounds__(256) void k_prep(const float* __restrict__ E, u16* __restrict__ X,
                                              const float* W0, const float* W1,
                                              const float* W2, const float* W3,
                                              u16* __restrict__ WT) {
  __shared__ __align__(16) u16 T[64*72];
  if (blockIdx.x < 2048) {                       // convert branch
    int idx = (blockIdx.x * 256 + threadIdx.x) * 8;
    float4 a = *(const float4*)(E + idx);
    float4 b = *(const float4*)(E + idx + 4);
    bf16x8 o;
    o[0]=f2bf(a.x); o[1]=f2bf(a.y); o[2]=f2bf(a.z); o[3]=f2bf(a.w);
    o[4]=f2bf(b.x); o[5]=f2bf(b.y); o[6]=f2bf(b.z); o[7]=f2bf(b.w);
    *(bf16x8*)(X + idx) = o;
    return;
  }
  int bz = blockIdx.x - 2048;
  int z = bz >> 8, rem = bz & 255, bx = rem & 15, by = rem >> 4;
  const float* W = (z==0)?W0:(z==1)?W1:(z==2)?W2:W3;
  u16* dst = WT + (size_t)z * HH * HH;
  int t = threadIdx.x;
  int n0 = bx * 64, k0 = by * 64;
  int kl = t >> 2, nc = t & 3;
  #pragma unroll
  for (int u = 0; u < 4; ++u) {
    float4 v = *(const float4*)(W + (size_t)(k0 + kl) * HH + n0 + nc*16 + u*4);
    int nb = nc*16 + u*4;
    T[(nb+0)*72 + kl] = f2bf(v.x);
    T[(nb+1)*72 + kl] = f2bf(v.y);
    T[(nb+2)*72 + kl] = f2bf(v.z);
    T[(nb+3)*72 + kl] = f2bf(v.w);
  }
  __syncthreads();
  int nl = t >> 2, kc = (t & 3) * 16;
  #pragma unroll
  for (int e = 0; e < 2; ++e) {
    bf16x8 v = *(const bf16x8*)(T + nl*72 + kc + e*8);
    *(bf16x8*)(dst + (size_t)(n0+nl)*HH + k0 + kc + e*8) = v;
  }
}

// ---------------- 128x128x(K=1024) bf16 QKV GEMM ----------------
// 3-slot LDS, 2-deep DMA prefetch, counted vmcnt(4) + raw s_barrier, chunk-XOR
// LDS swizzle (source-side pre-swizzle, linear DMA dest; read with gx).
// z=bn0>>10: 0=Q swapped, 1=K normal, 2=V swapped
__global__ __launch_bounds__(256) void k_gemm(const u16* __restrict__ A, const u16* __restrict__ Bt,
                                              const float* __restrict__ b0, const float* __restrict__ b1,
                                              const float* __restrict__ b2,
                                              u16* __restrict__ QH, u16* __restrict__ KV) {
  __shared__ __align__(16) u16 As[3][128*32];
  __shared__ __align__(16) u16 Bs[3][128*32];
  int tid = threadIdx.x;
  int lane = tid & 63, w = tid >> 6;
  int c = lane & 15, g = lane >> 4;
  int phys = blockIdx.x + blockIdx.y * 24;      // 768 blocks total
  int virt = (phys & 7) * 96 + (phys >> 3);     // bijective: 768 = 8*96
  int bxv = virt / 32, byv = virt - bxv * 32;   // n-major within XCD chunk
  int bn0 = bxv * 128, bm0 = byv * 128;
  int wm0 = (w >> 1) * 64, wn0 = (w & 1) * 64;
  int z = bn0 >> 10;
  bool swapd = (z != 1);                         // swapped: As<-weights, Bs<-tokens
  const u16* srcA = swapd ? Bt : A;
  const u16* srcB = swapd ? A : Bt;
  int baseA = swapd ? bn0 : bm0;
  int baseB = swapd ? bm0 : bn0;

  // staging geometry: LDS dest linear (DMA requirement); global source column
  // pre-swizzled by the involution chunk ^= (row>>1)&3.
  int ch0 = tid, ch1 = tid + 256;
  int sr0 = ch0 >> 2, sc0 = ((ch0 & 3) ^ ((ch0 >> 3) & 3)) * 8;
  int sr1 = ch1 >> 2, sc1 = ((ch1 & 3) ^ ((ch1 >> 3) & 3)) * 8;
  const u16* pa0 = srcA + (size_t)(baseA + sr0) * HH + sc0;
  const u16* pa1 = srcA + (size_t)(baseA + sr1) * HH + sc1;
  const u16* pb0 = srcB + (size_t)(baseB + sr0) * HH + sc0;
  const u16* pb1 = srcB + (size_t)(baseB + sr1) * HH + sc1;
  int gx = g ^ ((c >> 1) & 3);                   // swizzled chunk for frag reads

  f32x4 acc[4][4];
  #pragma unroll
  for (int mt = 0; mt < 4; ++mt)
    #pragma unroll
    for (int nt = 0; nt < 4; ++nt)
      acc[mt][nt] = (f32x4){0.f,0.f,0.f,0.f};

  // prologue: tiles 0,1 -> slots 0,1 (4 DMA instrs per wave per tile, in order)
  gload_lds16(pa0,      &As[0][ch0*8]);
  gload_lds16(pb0,      &Bs[0][ch0*8]);
  gload_lds16(pa1,      &As[0][ch1*8]);
  gload_lds16(pb1,      &Bs[0][ch1*8]);
  gload_lds16(pa0 + 32, &As[1][ch0*8]);
  gload_lds16(pb0 + 32, &Bs[1][ch0*8]);
  gload_lds16(pa1 + 32, &As[1][ch1*8]);
  gload_lds16(pb1 + 32, &Bs[1][ch1*8]);

  for (int kt = 0; kt < 32; ++kt) {
    // wait: oldest in-flight tile (kt) landed; tile kt+1 keeps flying.
    if (kt < 31) asm volatile("s_waitcnt vmcnt(4)" ::: "memory");
    else         asm volatile("s_waitcnt vmcnt(0)" ::: "memory");
    __builtin_amdgcn_s_barrier();               // all waves' tile-kt DMAs landed
    __builtin_amdgcn_sched_barrier(0);
    int cb = kt % 3;
    if (kt < 30) {                              // issue tile kt+2 into the slot
      int k0 = (kt + 2) * 32;                   // read during iter kt-1 (done)
      int nb = (kt + 2) % 3;
      gload_lds16(pa0 + k0, &As[nb][ch0*8]);
      gload_lds16(pb0 + k0, &Bs[nb][ch0*8]);
      gload_lds16(pa1 + k0, &As[nb][ch1*8]);
      gload_lds16(pb1 + k0, &Bs[nb][ch1*8]);
    }
    bf16x8 af[4], bfr[4];
    #pragma unroll
    for (int i = 0; i < 4; ++i) {
      af[i]  = *(const bf16x8*)(&As[cb][0] + (wm0 + i*16 + c)*32 + gx*8);
      bfr[i] = *(const bf16x8*)(&Bs[cb][0] + (wn0 + i*16 + c)*32 + gx*8);
    }
    #pragma unroll
    for (int mt = 0; mt < 4; ++mt)
      #pragma unroll
      for (int nt = 0; nt < 4; ++nt)
        acc[mt][nt] = __builtin_amdgcn_mfma_f32_16x16x32_bf16(af[mt], bfr[nt], acc[mt][nt], 0, 0, 0);
  }

  if (z == 1) {                                  // K, normal orientation -> K^T-sw tiles
    #pragma unroll
    for (int nt = 0; nt < 4; ++nt) {
      int n = bn0 + wn0 + nt*16 + c;
      int nn = n & 1023, h = nn >> 6, d = nn & 63;
      float bv = b1[nn];
      #pragma unroll
      for (int mt = 0; mt < 4; ++mt) {
        int m0 = bm0 + wm0 + mt*16 + 4*g;
        int b = m0 >> 11, keyl = m0 & 2047;
        int tt = keyl >> 6, chunk = (keyl >> 3) & 7, s = keyl & 7;
        u16x4 pk;
        #pragma unroll
        for (int r = 0; r < 4; ++r) pk[r] = f2bf(acc[mt][nt][r] + bv);
        *(u16x4*)(KV + ((size_t)((b*NH + h)*32 + tt))*8192 + d*64 + ((chunk ^ (d & 7))*8) + s) = pk;
      }
    }
  } else {                                       // Q / V, swapped orientation
    #pragma unroll
    for (int mt = 0; mt < 4; ++mt) {
      int nidx0 = bn0 + wm0 + mt*16 + 4*g;
      int nn0 = nidx0 & 1023, h = nn0 >> 6, d0 = nn0 & 63;
      const float* bp = (z == 0) ? b0 : b2;
      float4 bv = *(const float4*)(bp + nn0);
      #pragma unroll
      for (int nt = 0; nt < 4; ++nt) {
        int tok = bm0 + wn0 + nt*16 + c;
        int b = tok >> 11, l = tok & 2047;
        u16x4 o;
        o[0] = f2bf(acc[mt][nt][0] + bv.x);
        o[1] = f2bf(acc[mt][nt][1] + bv.y);
        o[2] = f2bf(acc[mt][nt][2] + bv.z);
        o[3] = f2bf(acc[mt][nt][3] + bv.w);
        if (z == 0) {
          *(u16x4*)(QH + (((size_t)(b*NH + h)) * LL + l) * HD + d0) = o;
        } else {
          int tt = l >> 6;
          *(u16x4*)(KV + ((size_t)((b*NH + h)*32 + tt))*8192 + 4096
                    + (l & 63)*64 + (((d0 >> 3) ^ (l & 7))*8) + (d0 & 7)) = o;
        }
      }
    }
  }
}

// ---------------- out-proj GEMM + fused combine: 64 tok x 64 n per block ------------
// v11: tile halved (128n -> 64n) so grid = 1024 blocks = 4 blocks/CU = 16 waves/CU
// (was 512 blocks = 2/CU = 25% occupancy, grid-limited). Same r5-proven simple
// structure: 2-slot As/Bs, syncthreads, combined load+normalize+ds_write staging.
// The doubled TLP covers the per-kt barrier drain that scheduling tricks couldn't.
__global__ __launch_bounds__(256) void k_gemm_o(const u16* __restrict__ PO0,
                                                const u16* __restrict__ PO1,
                                                const float* __restrict__ PL,
                                                const u16* __restrict__ Wt,
                                                const float* __restrict__ bias,
                                                float* __restrict__ outf) {
  __shared__ __align__(16) u16 As[2][64*32];     // weights: 64 n rows x 32 k
  __shared__ __align__(16) u16 Bs[2][64*32];     // tokens (combined+normalized)
  int tid = threadIdx.x;
  int lane = tid & 63, w = tid >> 6;
  int c = lane & 15, g = lane >> 4;
  int phys = blockIdx.x + (blockIdx.y << 4);     // 1024 blocks total
  int virt = (phys & 7) * 128 + (phys >> 3);     // bijective: 1024 = 8*128
  int bx = virt >> 6, by = virt & 63;            // n-major within XCD chunk
  int bn0 = bx * 64, bm0 = by * 64;
  int wm0 = (w >> 1) * 32, wn0 = (w & 1) * 32;
  // staging constants: thread owns (row, 8-col chunk), fixed across kt
  int row = tid >> 2, col = (tid & 3) * 8;
  int tok = bm0 + row, bb = tok >> 11, q = tok & 2047;
  const u16* pw = Wt + (size_t)(bn0 + row) * HH + col;

  f32x4 acc[2][2];
  #pragma unroll
  for (int mt = 0; mt < 2; ++mt)
    #pragma unroll
    for (int nt = 0; nt < 2; ++nt)
      acc[mt][nt] = (f32x4){0.f,0.f,0.f,0.f};

  // stage Bs[buf] for k-step kt: combine key-half partials + normalize, in regs
  auto stage_b = [&](int kt, int buf) {
    int kcb = kt * 32 + col;
    int h = kcb >> 6, d0 = kcb & 63;
    int bh = bb * NH + h;
    size_t po = ((size_t)bh * LL + q) * HD + d0;
    bf16x8 a0 = *(const bf16x8*)(PO0 + po);
    bf16x8 a1 = *(const bf16x8*)(PO1 + po);
    float inv = 1.0f / (PL[(size_t)bh * LL + q] + PL[(size_t)(32 + bh) * LL + q]);
    bf16x8 o;
    #pragma unroll
    for (int i = 0; i < 8; ++i)
      o[i] = (short)f2bf((bf2f((u16)a0[i]) + bf2f((u16)a1[i])) * inv);
    *(bf16x8*)(&Bs[buf][tid*8]) = o;
  };

  gload_lds16(pw, &As[0][tid*8]);                // prologue: As kt=0 (1 chunk/thread)
  stage_b(0, 0);                                 // Bs kt=0, reg path

  for (int kt = 0; kt < 32; ++kt) {
    __syncthreads();
    int cb = kt & 1;
    if (kt < 31) {
      int k0 = (kt + 1) * 32, nb = (kt + 1) & 1;
      gload_lds16(pw + k0, &As[nb][tid*8]);
      stage_b(kt + 1, nb);
    }
    bf16x8 af[2], bfr[2];
    #pragma unroll
    for (int i = 0; i < 2; ++i)
      af[i] = *(const bf16x8*)(&As[cb][0] + (wm0 + i*16 + c)*32 + g*8);
    #pragma unroll
    for (int j = 0; j < 2; ++j)
      bfr[j] = *(const bf16x8*)(&Bs[cb][0] + (wn0 + j*16 + c)*32 + g*8);
    #pragma unroll
    for (int mt = 0; mt < 2; ++mt)
      #pragma unroll
      for (int nt = 0; nt < 2; ++nt)
        acc[mt][nt] = __builtin_amdgcn_mfma_f32_16x16x32_bf16(af[mt], bfr[nt], acc[mt][nt], 0, 0, 0);
  }
  #pragma unroll
  for (int mt = 0; mt < 2; ++mt) {
    int n0 = bn0 + wm0 + mt*16 + 4*g;
    float4 bv = *(const float4*)(bias + n0);
    #pragma unroll
    for (int nt = 0; nt < 2; ++nt) {
      int t2 = bm0 + wn0 + nt*16 + c;
      float4 o;
      o.x = acc[mt][nt][0] + bv.x;
      o.y = acc[mt][nt][1] + bv.y;
      o.z = acc[mt][nt][2] + bv.z;
      o.w = acc[mt][nt][3] + bv.w;
      *(float4*)(outf + (size_t)t2 * HH + n0) = o;
    }
  }
}

// ---------------- flash attention (r5-proven): dbuf sKV + in-register P + raw v_exp ----
// 256 thr, 4 waves x 32q, key-split x2, 4 blocks/CU. S^T = mfma(V, Q) so each lane
// holds P^T[kv][q] with q on lane&15; cvt_pk + permlane32/16_swap build PV B-frags
// in-register. 1 barrier/tile, prefetch-after-barrier.
__global__ __launch_bounds__(256, 4) void k_attn(const u16* __restrict__ QH, const u16* __restrict__ KV,
                                              const float* __restrict__ mask,
                                              u16* __restrict__ PO0, u16* __restrict__ PO1,
                                              float* __restrict__ PL) {
  __shared__ __align__(16) u16 sKV[2][8192];    // [0,4096) K^T-sw, [4096,8192) V-sw, x2 dbuf
  int tid = threadIdx.x;
  int lane = tid & 63, w = tid >> 6;
  int c = lane & 15, g = lane >> 4;
  // XCD-aware bijective swizzle: 1024 blocks -> 128-block contiguous chunk per XCD.
  int phys = blockIdx.x + (blockIdx.y << 4) + (blockIdx.z << 5);
  int virt = (phys & 7) * 128 + (phys >> 3);
  int bx = virt & 15;
  int z = (virt >> 4) & 1;                      // key half
  int bh = virt >> 5, b = bh >> 4;
  int q0 = bx * 128 + w * 32;                   // this wave's 32 q-rows
  size_t qbase = (size_t)bh * LL * HD;
  const u16* kvg = KV + (size_t)bh * 32 * 8192 + (size_t)z * 16 * 8192;
  const float* mptr = mask + b * LL + z * 1024;

  bf16x8 aq[2][2];
  #pragma unroll
  for (int qi = 0; qi < 2; ++qi)
    #pragma unroll
    for (int ks = 0; ks < 2; ++ks)
      aq[qi][ks] = *(const bf16x8*)(QH + qbase + (size_t)(q0 + qi*16 + c) * HD + ks*32 + g*8);

  bf16x8 ones;
  #pragma unroll
  for (int i = 0; i < 8; ++i) ones[i] = (short)0x3F80;   // bf16 1.0

  f32x4 O[2][4], lac[2];
  #pragma unroll
  for (int qi = 0; qi < 2; ++qi) {
    lac[qi] = (f32x4){0.f,0.f,0.f,0.f};
    #pragma unroll
    for (int dt = 0; dt < 4; ++dt) O[qi][dt] = (f32x4){0.f,0.f,0.f,0.f};
  }

  #pragma unroll
  for (int it = 0; it < 4; ++it) {              // prologue: tile 0 -> buf 0
    int i = (tid + it*256) * 8;
    gload_lds16(kvg + i, &sKV[0][0] + i);
  }

  for (int tt = 0; tt < 16; ++tt) {
    __syncthreads();                            // drains tile-tt DMA; syncs all waves
    int cb = tt & 1;
    if (tt < 15) {                              // prefetch tt+1 into other buffer
      #pragma unroll
      for (int it = 0; it < 4; ++it) {
        int i = (tid + it*256) * 8;
        gload_lds16(kvg + (size_t)(tt+1)*8192 + i, &sKV[cb^1][0] + i);
      }
    }
    const u16* kvp = &sKV[cb][0];
    int kv0 = tt * 64;

    // ---- S^T = V * Q^T; P^T = exp2(...) held per-lane, packed to bf16 dwords ----
    unsigned X[2][4][2];                        // [qi][nt][u]: dword = kv pair (4g+2u, 4g+2u+1)
    #pragma unroll
    for (int nt = 0; nt < 4; ++nt) {
      int vrow = nt*16 + c;
      bf16x8 vb0 = *(const bf16x8*)(kvp + 4096 + vrow*64 + ((g ^ (c & 7))*8));
      bf16x8 vb1 = *(const bf16x8*)(kvp + 4096 + vrow*64 + (((4 + g) ^ (c & 7))*8));
      float4 mv = *(const float4*)(mptr + kv0 + nt*16 + 4*g);   // mask per kv row
      float mt0 = fmaf(mv.x, LOG2E, -C_SHIFT);
      float mt1 = fmaf(mv.y, LOG2E, -C_SHIFT);
      float mt2 = fmaf(mv.z, LOG2E, -C_SHIFT);
      float mt3 = fmaf(mv.w, LOG2E, -C_SHIFT);
      #pragma unroll
      for (int qi = 0; qi < 2; ++qi) {
        f32x4 sa = (f32x4){0.f,0.f,0.f,0.f};
        sa = __builtin_amdgcn_mfma_f32_16x16x32_bf16(vb0, aq[qi][0], sa, 0,0,0);
        sa = __builtin_amdgcn_mfma_f32_16x16x32_bf16(vb1, aq[qi][1], sa, 0,0,0);
        float p0 = fast_exp2(fmaf(sa[0], C_QSCALE, mt0));
        float p1 = fast_exp2(fmaf(sa[1], C_QSCALE, mt1));
        float p2 = fast_exp2(fmaf(sa[2], C_QSCALE, mt2));
        float p3 = fast_exp2(fmaf(sa[3], C_QSCALE, mt3));
        X[qi][nt][0] = cvt_pk_bf16(p0, p1);
        X[qi][nt][1] = cvt_pk_bf16(p2, p3);
      }
    }
    // ---- lane-row exchange: X -> PV B-frags ----
    bf16x8 ap[2][2];
    #pragma unroll
    for (int qi = 0; qi < 2; ++qi) {
      #pragma unroll
      for (int h = 0; h < 2; ++h) {
        unsigned x0 = X[qi][2*h][0],   x1 = X[qi][2*h][1];
        unsigned x2 = X[qi][2*h+1][0], x3 = X[qi][2*h+1][1];
        pl32swap(x0, x2); pl16swap(x0, x2);     // x0=A0 (kv 8g+0,1) x2=A2 (kv 8g+4,5)
        pl32swap(x1, x3); pl16swap(x1, x3);     // x1=A1 (kv 8g+2,3) x3=A3 (kv 8g+6,7)
        union { u32x4 u; bf16x8 b; } cvt;
        cvt.u[0] = x0; cvt.u[1] = x1; cvt.u[2] = x2; cvt.u[3] = x3;
        ap[qi][h] = cvt.b;
        lac[qi] = __builtin_amdgcn_mfma_f32_16x16x32_bf16(ones, ap[qi][h], lac[qi], 0,0,0);
      }
    }
    // ---- O^T += K^T-frag * P (d-major out) ----
    #pragma unroll
    for (int dt = 0; dt < 4; ++dt) {
      int d = dt*16 + c;
      bf16x8 bk0 = *(const bf16x8*)(kvp + d*64 + ((g ^ (c & 7))*8));
      bf16x8 bk1 = *(const bf16x8*)(kvp + d*64 + (((4 + g) ^ (c & 7))*8));
      #pragma unroll
      for (int qi = 0; qi < 2; ++qi) {
        O[qi][dt] = __builtin_amdgcn_mfma_f32_16x16x32_bf16(bk0, ap[qi][0], O[qi][dt], 0,0,0);
        O[qi][dt] = __builtin_amdgcn_mfma_f32_16x16x32_bf16(bk1, ap[qi][1], O[qi][dt], 0,0,0);
      }
    }
  }
  u16* POp = (z == 0) ? PO0 : PO1;
  #pragma unroll
  for (int qi = 0; qi < 2; ++qi) {
    int q = q0 + qi*16 + c;
    size_t qrow = (size_t)bh * LL + q;
    if (g == 0) PL[(size_t)(z*32 + bh) * LL + q] = lac[qi][0];   // col-sums: rows equal
    #pragma unroll
    for (int dt = 0; dt < 4; ++dt) {
      u16x4 o;
      #pragma unroll
      for (int r = 0; r < 4; ++r) o[r] = f2bf(O[qi][dt][r]);
      *(u16x4*)(POp + qrow*HD + dt*16 + 4*g) = o;
    }
  }
}

// ---------------- residual + LayerNorm -> fp32 out ----------------
__global__ __launch_bounds__(256) void k_ln(const float* __restrict__ OF, const float* __restrict__ E,
                                            const float* __restrict__ gamma, const float* __restrict__ beta,
                                            float* __restrict__ out) {
  int row = blockIdx.x;
  int tid = threadIdx.x, lane = tid & 63, w = tid >> 6;
  size_t basei = (size_t)row * HH + tid*4;
  float4 a = *(const float4*)(OF + basei);
  float4 e = *(const float4*)(E + basei);
  float x0 = a.x + e.x, x1 = a.y + e.y, x2 = a.z + e.z, x3 = a.w + e.w;
  float s1 = x0+x1+x2+x3;
  float s2 = x0*x0+x1*x1+x2*x2+x3*x3;
  #pragma unroll
  for (int off = 32; off; off >>= 1) { s1 += __shfl_xor(s1, off); s2 += __shfl_xor(s2, off); }
  __shared__ float r1[4], r2[4];
  if (lane == 0) { r1[w] = s1; r2[w] = s2; }
  __syncthreads();
  s1 = r1[0]+r1[1]+r1[2]+r1[3];
  s2 = r2[0]+r2[1]+r2[2]+r2[3];
  float mu = s1 * (1.0f/HH);
  float var = s2 * (1.0f/HH) - mu*mu;
  float rs = rsqrtf(fmaxf(var, 0.f) + 1e-12f);
  int colb = tid*4;
  float4 gm = *(const float4*)(gamma + colb);
  float4 bt = *(const float4*)(beta + colb);
  float4 o;
  o.x = (x0-mu)*rs*gm.x + bt.x;
  o.y = (x1-mu)*rs*gm.y + bt.y;
  o.z = (x2-mu)*rs*gm.z + bt.z;
  o.w = (x3-mu)*rs*gm.w + bt.w;
  *(float4*)(out + basei) = o;
}

extern "C" void kernel_launch(void* const* d_in, const int* in_sizes, int n_in,
                              void* d_out, int out_size, void* d_ws, size_t ws_size,
                              hipStream_t stream) {
  const float* E    = (const float*)d_in[0];
  const float* mask = (const float*)d_in[1];
  const float* Wq   = (const float*)d_in[2];
  const float* bq   = (const float*)d_in[3];
  const float* Wk   = (const float*)d_in[4];
  const float* bk   = (const float*)d_in[5];
  const float* Wv   = (const float*)d_in[6];
  const float* bv   = (const float*)d_in[7];
  const float* Wo   = (const float*)d_in[8];
  const float* bo   = (const float*)d_in[9];
  const float* gam  = (const float*)d_in[10];
  const float* bet  = (const float*)d_in[11];

  const size_t MH = (size_t)ML * HH;      // 4M elems
  u16* XBF = (u16*)d_ws;                  // 8 MB bf16 embeddings (dead after QKV gemm)
  u16* WT  = XBF + MH;                    // 8 MB: Wq^T,Wk^T,Wv^T,Wo^T bf16 [n][k]
  u16* QH  = WT + 4*(size_t)HH*HH;        // 8 MB, [bh][l][d] (dead after k_attn)
  u16* KV  = QH + MH;                     // 16 MB (dead after k_attn)
  u16* PO0 = KV + 2*MH;                   // 8 MB partial O, key half 0 (live through k_gemm_o)
  u16* PO1 = PO0 + MH;                    // 8 MB partial O, key half 1 (live through k_gemm_o)
  float* out = (float*)d_out;
  float* PL = out;                        // 512 KB partial l in d_out (consumed by k_gemm_o; k_ln overwrites)
  float* OF = (float*)QH;                 // 16 MB fp32, overlays QH+KV (both dead after k_attn)

  k_prep<<<dim3(3072), 256, 0, stream>>>(E, XBF, Wq, Wk, Wv, Wo, WT);
  k_gemm<<<dim3(24,32), 256, 0, stream>>>(XBF, WT, bq, bk, bv, QH, KV);
  k_attn<<<dim3(16,2,32), 256, 0, stream>>>(QH, KV, mask, PO0, PO1, PL);
  k_gemm_o<<<dim3(16,64), 256, 0, stream>>>(PO0, PO1, PL, WT + 3*(size_t)HH*HH, bo, OF);
  k_ln<<<dim3(ML), 256, 0, stream>>>(OF, E, gam, bet, out);
}

// Round 12
// 222.352 us; speedup vs baseline: 1.0352x; 1.0352x over previous
//
#include <hip/hip_runtime.h>

#define LOG2E 1.44269504f
#define C_QSCALE 0.360673760f   // 0.25 * log2(e)
#define C_SHIFT  34.6246810f    // 24 * log2(e)
typedef unsigned short u16;
typedef short bf16x8 __attribute__((ext_vector_type(8)));
typedef float f32x4 __attribute__((ext_vector_type(4)));
typedef unsigned short u16x4 __attribute__((ext_vector_type(4)));
typedef unsigned int u32x4 __attribute__((ext_vector_type(4)));

#define BB 2
#define LL 2048
#define HH 1024
#define NH 16
#define HD 64
#define ML (BB*LL)   // 4096 rows total

__device__ __forceinline__ u16 f2bf(float f) {   // round-to-nearest-even
  union { float f; unsigned u; } v; v.f = f;
  unsigned r = v.u + 0x7FFFu + ((v.u >> 16) & 1u);
  return (u16)(r >> 16);
}
__device__ __forceinline__ float bf2f(u16 u) {
  union { unsigned u; float f; } v; v.u = ((unsigned)u) << 16;
  return v.f;
}
__device__ __forceinline__ void gload_lds16(const u16* g, u16* l) {
  __builtin_amdgcn_global_load_lds((const __attribute__((address_space(1))) void*)g,
                                   (__attribute__((address_space(3))) void*)l, 16, 0, 0);
}
// raw hardware exp2 (v_exp_f32): skips the OCML denormal-range fixup (~15 VALU
// instrs/call -> 1). Underflow flushes toward 0, correct for fixed-shift softmax.
// Verified numerically (absmax unchanged at 0.03125).
__device__ __forceinline__ float fast_exp2(float x) {
  float r; asm("v_exp_f32 %0, %1" : "=v"(r) : "v"(x)); return r;
}
// pack two f32 -> one dword of 2 bf16 (src0 in low half), RNE
__device__ __forceinline__ unsigned cvt_pk_bf16(float lo, float hi) {
  unsigned r;
  asm("v_cvt_pk_bf16_f32 %0, %1, %2" : "=v"(r) : "v"(lo), "v"(hi));
  return r;
}
// a_new = {a.r0, b.r0, a.r2, b.r2}; b_new = {a.r1, b.r1, a.r3, b.r3}  (16-lane rows)
__device__ __forceinline__ void pl16swap(unsigned &a, unsigned &b) {
  asm("v_permlane16_swap_b32 %0, %1" : "+v"(a), "+v"(b));
}
// a_new = {a.lo32, b.lo32}; b_new = {a.hi32, b.hi32}
__device__ __forceinline__ void pl32swap(unsigned &a, unsigned &b) {
  asm("v_permlane32_swap_b32 %0, %1" : "+v"(a), "+v"(b));
}

// ---------------- merged: E fp32->bf16 convert  +  W transpose->bf16 ----------------
__global__ __launch_bounds__(256) void k_prep(const float* __restrict__ E, u16* __restrict__ X,
                                              const float* W0, const float* W1,
                                              const float* W2, const float* W3,
                                              u16* __restrict__ WT) {
  __shared__ __align__(16) u16 T[64*72];
  if (blockIdx.x < 2048) {                       // convert branch
    int idx = (blockIdx.x * 256 + threadIdx.x) * 8;
    float4 a = *(const float4*)(E + idx);
    float4 b = *(const float4*)(E + idx + 4);
    bf16x8 o;
    o[0]=f2bf(a.x); o[1]=f2bf(a.y); o[2]=f2bf(a.z); o[3]=f2bf(a.w);
    o[4]=f2bf(b.x); o[5]=f2bf(b.y); o[6]=f2bf(b.z); o[7]=f2bf(b.w);
    *(bf16x8*)(X + idx) = o;
    return;
  }
  int bz = blockIdx.x - 2048;
  int z = bz >> 8, rem = bz & 255, bx = rem & 15, by = rem >> 4;
  const float* W = (z==0)?W0:(z==1)?W1:(z==2)?W2:W3;
  u16* dst = WT + (size_t)z * HH * HH;
  int t = threadIdx.x;
  int n0 = bx * 64, k0 = by * 64;
  int kl = t >> 2, nc = t & 3;
  #pragma unroll
  for (int u = 0; u < 4; ++u) {
    float4 v = *(const float4*)(W + (size_t)(k0 + kl) * HH + n0 + nc*16 + u*4);
    int nb = nc*16 + u*4;
    T[(nb+0)*72 + kl] = f2bf(v.x);
    T[(nb+1)*72 + kl] = f2bf(v.y);
    T[(nb+2)*72 + kl] = f2bf(v.z);
    T[(nb+3)*72 + kl] = f2bf(v.w);
  }
  __syncthreads();
  int nl = t >> 2, kc = (t & 3) * 16;
  #pragma unroll
  for (int e = 0; e < 2; ++e) {
    bf16x8 v = *(const bf16x8*)(T + nl*72 + kc + e*8);
    *(bf16x8*)(dst + (size_t)(n0+nl)*HH + k0 + kc + e*8) = v;
  }
}

// ---------------- 128x128x(K=1024) bf16 QKV GEMM ----------------
// 3-slot LDS, 2-deep DMA prefetch, counted vmcnt(4) + raw s_barrier (never drains
// the in-flight prefetch -> staging latency off the critical path), chunk-XOR LDS
// swizzle (source-side pre-swizzle, linear DMA dest; read with gx).
// z=bn0>>10: 0=Q swapped, 1=K normal, 2=V swapped
__global__ __launch_bounds__(256) void k_gemm(const u16* __restrict__ A, const u16* __restrict__ Bt,
                                              const float* __restrict__ b0, const float* __restrict__ b1,
                                              const float* __restrict__ b2,
                                              u16* __restrict__ QH, u16* __restrict__ KV) {
  __shared__ __align__(16) u16 As[3][128*32];
  __shared__ __align__(16) u16 Bs[3][128*32];
  int tid = threadIdx.x;
  int lane = tid & 63, w = tid >> 6;
  int c = lane & 15, g = lane >> 4;
  int phys = blockIdx.x + blockIdx.y * 24;      // 768 blocks total
  int virt = (phys & 7) * 96 + (phys >> 3);     // bijective: 768 = 8*96
  int bxv = virt / 32, byv = virt - bxv * 32;   // n-major within XCD chunk
  int bn0 = bxv * 128, bm0 = byv * 128;
  int wm0 = (w >> 1) * 64, wn0 = (w & 1) * 64;
  int z = bn0 >> 10;
  bool swapd = (z != 1);                         // swapped: As<-weights, Bs<-tokens
  const u16* srcA = swapd ? Bt : A;
  const u16* srcB = swapd ? A : Bt;
  int baseA = swapd ? bn0 : bm0;
  int baseB = swapd ? bm0 : bn0;

  // staging geometry: LDS dest linear (DMA requirement); global source column
  // pre-swizzled by the involution chunk ^= (row>>1)&3.
  int ch0 = tid, ch1 = tid + 256;
  int sr0 = ch0 >> 2, sc0 = ((ch0 & 3) ^ ((ch0 >> 3) & 3)) * 8;
  int sr1 = ch1 >> 2, sc1 = ((ch1 & 3) ^ ((ch1 >> 3) & 3)) * 8;
  const u16* pa0 = srcA + (size_t)(baseA + sr0) * HH + sc0;
  const u16* pa1 = srcA + (size_t)(baseA + sr1) * HH + sc1;
  const u16* pb0 = srcB + (size_t)(baseB + sr0) * HH + sc0;
  const u16* pb1 = srcB + (size_t)(baseB + sr1) * HH + sc1;
  int gx = g ^ ((c >> 1) & 3);                   // swizzled chunk for frag reads

  f32x4 acc[4][4];
  #pragma unroll
  for (int mt = 0; mt < 4; ++mt)
    #pragma unroll
    for (int nt = 0; nt < 4; ++nt)
      acc[mt][nt] = (f32x4){0.f,0.f,0.f,0.f};

  // prologue: tiles 0,1 -> slots 0,1 (4 DMA instrs per wave per tile, in order)
  gload_lds16(pa0,      &As[0][ch0*8]);
  gload_lds16(pb0,      &Bs[0][ch0*8]);
  gload_lds16(pa1,      &As[0][ch1*8]);
  gload_lds16(pb1,      &Bs[0][ch1*8]);
  gload_lds16(pa0 + 32, &As[1][ch0*8]);
  gload_lds16(pb0 + 32, &Bs[1][ch0*8]);
  gload_lds16(pa1 + 32, &As[1][ch1*8]);
  gload_lds16(pb1 + 32, &Bs[1][ch1*8]);

  for (int kt = 0; kt < 32; ++kt) {
    // wait: oldest in-flight tile (kt) landed; tile kt+1 keeps flying.
    if (kt < 31) asm volatile("s_waitcnt vmcnt(4)" ::: "memory");
    else         asm volatile("s_waitcnt vmcnt(0)" ::: "memory");
    __builtin_amdgcn_s_barrier();               // all waves' tile-kt DMAs landed
    __builtin_amdgcn_sched_barrier(0);
    int cb = kt % 3;
    if (kt < 30) {                              // issue tile kt+2 into the slot
      int k0 = (kt + 2) * 32;                   // read during iter kt-1 (done)
      int nb = (kt + 2) % 3;
      gload_lds16(pa0 + k0, &As[nb][ch0*8]);
      gload_lds16(pb0 + k0, &Bs[nb][ch0*8]);
      gload_lds16(pa1 + k0, &As[nb][ch1*8]);
      gload_lds16(pb1 + k0, &Bs[nb][ch1*8]);
    }
    bf16x8 af[4], bfr[4];
    #pragma unroll
    for (int i = 0; i < 4; ++i) {
      af[i]  = *(const bf16x8*)(&As[cb][0] + (wm0 + i*16 + c)*32 + gx*8);
      bfr[i] = *(const bf16x8*)(&Bs[cb][0] + (wn0 + i*16 + c)*32 + gx*8);
    }
    #pragma unroll
    for (int mt = 0; mt < 4; ++mt)
      #pragma unroll
      for (int nt = 0; nt < 4; ++nt)
        acc[mt][nt] = __builtin_amdgcn_mfma_f32_16x16x32_bf16(af[mt], bfr[nt], acc[mt][nt], 0, 0, 0);
  }

  if (z == 1) {                                  // K, normal orientation -> K^T-sw tiles
    #pragma unroll
    for (int nt = 0; nt < 4; ++nt) {
      int n = bn0 + wn0 + nt*16 + c;
      int nn = n & 1023, h = nn >> 6, d = nn & 63;
      float bv = b1[nn];
      #pragma unroll
      for (int mt = 0; mt < 4; ++mt) {
        int m0 = bm0 + wm0 + mt*16 + 4*g;
        int b = m0 >> 11, keyl = m0 & 2047;
        int tt = keyl >> 6, chunk = (keyl >> 3) & 7, s = keyl & 7;
        u16x4 pk;
        #pragma unroll
        for (int r = 0; r < 4; ++r) pk[r] = f2bf(acc[mt][nt][r] + bv);
        *(u16x4*)(KV + ((size_t)((b*NH + h)*32 + tt))*8192 + d*64 + ((chunk ^ (d & 7))*8) + s) = pk;
      }
    }
  } else {                                       // Q / V, swapped orientation
    #pragma unroll
    for (int mt = 0; mt < 4; ++mt) {
      int nidx0 = bn0 + wm0 + mt*16 + 4*g;
      int nn0 = nidx0 & 1023, h = nn0 >> 6, d0 = nn0 & 63;
      const float* bp = (z == 0) ? b0 : b2;
      float4 bv = *(const float4*)(bp + nn0);
      #pragma unroll
      for (int nt = 0; nt < 4; ++nt) {
        int tok = bm0 + wn0 + nt*16 + c;
        int b = tok >> 11, l = tok & 2047;
        u16x4 o;
        o[0] = f2bf(acc[mt][nt][0] + bv.x);
        o[1] = f2bf(acc[mt][nt][1] + bv.y);
        o[2] = f2bf(acc[mt][nt][2] + bv.z);
        o[3] = f2bf(acc[mt][nt][3] + bv.w);
        if (z == 0) {
          *(u16x4*)(QH + (((size_t)(b*NH + h)) * LL + l) * HD + d0) = o;
        } else {
          int tt = l >> 6;
          *(u16x4*)(KV + ((size_t)((b*NH + h)*32 + tt))*8192 + 4096
                    + (l & 63)*64 + (((d0 >> 3) ^ (l & 7))*8) + (d0 & 7)) = o;
        }
      }
    }
  }
}

// ---------------- out-proj GEMM + fused combine: 64 tok x 128 n per block ----------
// Bs is reg-staged directly from the attention partials: (PO0+PO1)*inv[tok][h],
// eliminating the separate k_combine kernel and the ATT round-trip. As (weights)
// stays on the gload_lds DMA path. XCD swizzle: 1 n-column (256KB weight panel)
// per XCD, tokens stream.
__global__ __launch_bounds__(256) void k_gemm_o(const u16* __restrict__ PO0,
                                                const u16* __restrict__ PO1,
                                                const float* __restrict__ PL,
                                                const u16* __restrict__ Wt,
                                                const float* __restrict__ bias,
                                                float* __restrict__ outf) {
  __shared__ __align__(16) u16 As[2][128*32];    // weights: n rows x k
  __shared__ __align__(16) u16 Bs[2][64*32];     // tokens (combined+normalized)
  int tid = threadIdx.x;
  int lane = tid & 63, w = tid >> 6;
  int c = lane & 15, g = lane >> 4;
  int phys = blockIdx.x + (blockIdx.y << 3);     // 512 blocks total
  int virt = (phys & 7) * 64 + (phys >> 3);      // bijective: 512 = 8*64
  int bx = virt >> 6, by = virt & 63;            // n-major within XCD chunk
  int bn0 = bx * 128, bm0 = by * 64;
  int wm0 = (w >> 1) * 64, wn0 = (w & 1) * 32;
  // Bs reg-staging constants: thread owns (token row, 8-col chunk), fixed across kt
  int row = tid >> 2, col = (tid & 3) * 8;
  int tok = bm0 + row, bb = tok >> 11, q = tok & 2047;

  f32x4 acc[4][2];
  #pragma unroll
  for (int mt = 0; mt < 4; ++mt)
    #pragma unroll
    for (int nt = 0; nt < 2; ++nt)
      acc[mt][nt] = (f32x4){0.f,0.f,0.f,0.f};

  // stage Bs[buf] for k-step kt: combine key-half partials + normalize, in regs
  auto stage_b = [&](int kt, int buf) {
    int kcb = kt * 32 + col;
    int h = kcb >> 6, d0 = kcb & 63;
    int bh = bb * NH + h;
    size_t po = ((size_t)bh * LL + q) * HD + d0;
    bf16x8 a0 = *(const bf16x8*)(PO0 + po);
    bf16x8 a1 = *(const bf16x8*)(PO1 + po);
    float inv = 1.0f / (PL[(size_t)bh * LL + q] + PL[(size_t)(32 + bh) * LL + q]);
    bf16x8 o;
    #pragma unroll
    for (int i = 0; i < 8; ++i)
      o[i] = (short)f2bf((bf2f((u16)a0[i]) + bf2f((u16)a1[i])) * inv);
    *(bf16x8*)(&Bs[buf][tid*8]) = o;
  };

  #pragma unroll
  for (int it = 0; it < 2; ++it) {               // prologue: As 512 chunks via DMA
    int ch = tid + it*256, r2 = ch >> 2, c2 = (ch & 3) * 8;
    gload_lds16(Wt + (size_t)(bn0 + r2) * HH + c2, &As[0][ch*8]);
  }
  stage_b(0, 0);                                 // Bs kt=0, reg path

  for (int kt = 0; kt < 32; ++kt) {
    __syncthreads();
    int cb = kt & 1;
    if (kt < 31) {
      int k0 = (kt + 1) * 32, nb = (kt + 1) & 1;
      #pragma unroll
      for (int it = 0; it < 2; ++it) {
        int ch = tid + it*256, r2 = ch >> 2, c2 = (ch & 3) * 8;
        gload_lds16(Wt + (size_t)(bn0 + r2) * HH + k0 + c2, &As[nb][ch*8]);
      }
      stage_b(kt + 1, nb);
    }
    bf16x8 af[4], bfr[2];
    #pragma unroll
    for (int i = 0; i < 4; ++i)
      af[i] = *(const bf16x8*)(&As[cb][0] + (wm0 + i*16 + c)*32 + g*8);
    #pragma unroll
    for (int j = 0; j < 2; ++j)
      bfr[j] = *(const bf16x8*)(&Bs[cb][0] + (wn0 + j*16 + c)*32 + g*8);
    #pragma unroll
    for (int mt = 0; mt < 4; ++mt)
      #pragma unroll
      for (int nt = 0; nt < 2; ++nt)
        acc[mt][nt] = __builtin_amdgcn_mfma_f32_16x16x32_bf16(af[mt], bfr[nt], acc[mt][nt], 0, 0, 0);
  }
  #pragma unroll
  for (int mt = 0; mt < 4; ++mt) {
    int n0 = bn0 + wm0 + mt*16 + 4*g;
    float4 bv = *(const float4*)(bias + n0);
    #pragma unroll
    for (int nt = 0; nt < 2; ++nt) {
      int t2 = bm0 + wn0 + nt*16 + c;
      float4 o;
      o.x = acc[mt][nt][0] + bv.x;
      o.y = acc[mt][nt][1] + bv.y;
      o.z = acc[mt][nt][2] + bv.z;
      o.w = acc[mt][nt][3] + bv.w;
      *(float4*)(outf + (size_t)t2 * HH + n0) = o;
    }
  }
}

// ---------------- flash attention (session optimum): dbuf sKV + in-register P ----
// 256 thr, 4 waves x 32q, key-split x2, 4 blocks/CU. S^T = mfma(V, Q) so each lane
// holds P^T[kv][q] with q on lane&15; cvt_pk + permlane32/16_swap build PV B-frags
// in-register. 1 barrier/tile, prefetch-after-barrier. Raw v_exp_f32 softmax.
__global__ __launch_bounds__(256, 4) void k_attn(const u16* __restrict__ QH, const u16* __restrict__ KV,
                                              const float* __restrict__ mask,
                                              u16* __restrict__ PO0, u16* __restrict__ PO1,
                                              float* __restrict__ PL) {
  __shared__ __align__(16) u16 sKV[2][8192];    // [0,4096) K^T-sw, [4096,8192) V-sw, x2 dbuf
  int tid = threadIdx.x;
  int lane = tid & 63, w = tid >> 6;
  int c = lane & 15, g = lane >> 4;
  // XCD-aware bijective swizzle: 1024 blocks -> 128-block contiguous chunk per XCD.
  int phys = blockIdx.x + (blockIdx.y << 4) + (blockIdx.z << 5);
  int virt = (phys & 7) * 128 + (phys >> 3);
  int bx = virt & 15;
  int z = (virt >> 4) & 1;                      // key half
  int bh = virt >> 5, b = bh >> 4;
  int q0 = bx * 128 + w * 32;                   // this wave's 32 q-rows
  size_t qbase = (size_t)bh * LL * HD;
  const u16* kvg = KV + (size_t)bh * 32 * 8192 + (size_t)z * 16 * 8192;
  const float* mptr = mask + b * LL + z * 1024;

  bf16x8 aq[2][2];
  #pragma unroll
  for (int qi = 0; qi < 2; ++qi)
    #pragma unroll
    for (int ks = 0; ks < 2; ++ks)
      aq[qi][ks] = *(const bf16x8*)(QH + qbase + (size_t)(q0 + qi*16 + c) * HD + ks*32 + g*8);

  bf16x8 ones;
  #pragma unroll
  for (int i = 0; i < 8; ++i) ones[i] = (short)0x3F80;   // bf16 1.0

  f32x4 O[2][4], lac[2];
  #pragma unroll
  for (int qi = 0; qi < 2; ++qi) {
    lac[qi] = (f32x4){0.f,0.f,0.f,0.f};
    #pragma unroll
    for (int dt = 0; dt < 4; ++dt) O[qi][dt] = (f32x4){0.f,0.f,0.f,0.f};
  }

  #pragma unroll
  for (int it = 0; it < 4; ++it) {              // prologue: tile 0 -> buf 0
    int i = (tid + it*256) * 8;
    gload_lds16(kvg + i, &sKV[0][0] + i);
  }

  for (int tt = 0; tt < 16; ++tt) {
    __syncthreads();                            // drains tile-tt DMA; syncs all waves
    int cb = tt & 1;
    if (tt < 15) {                              // prefetch tt+1 into other buffer
      #pragma unroll
      for (int it = 0; it < 4; ++it) {
        int i = (tid + it*256) * 8;
        gload_lds16(kvg + (size_t)(tt+1)*8192 + i, &sKV[cb^1][0] + i);
      }
    }
    const u16* kvp = &sKV[cb][0];
    int kv0 = tt * 64;

    // ---- S^T = V * Q^T; P^T = exp2(...) held per-lane, packed to bf16 dwords ----
    unsigned X[2][4][2];                        // [qi][nt][u]: dword = kv pair (4g+2u, 4g+2u+1)
    #pragma unroll
    for (int nt = 0; nt < 4; ++nt) {
      int vrow = nt*16 + c;
      bf16x8 vb0 = *(const bf16x8*)(kvp + 4096 + vrow*64 + ((g ^ (c & 7))*8));
      bf16x8 vb1 = *(const bf16x8*)(kvp + 4096 + vrow*64 + (((4 + g) ^ (c & 7))*8));
      float4 mv = *(const float4*)(mptr + kv0 + nt*16 + 4*g);   // mask per kv row
      float mt0 = fmaf(mv.x, LOG2E, -C_SHIFT);
      float mt1 = fmaf(mv.y, LOG2E, -C_SHIFT);
      float mt2 = fmaf(mv.z, LOG2E, -C_SHIFT);
      float mt3 = fmaf(mv.w, LOG2E, -C_SHIFT);
      #pragma unroll
      for (int qi = 0; qi < 2; ++qi) {
        f32x4 sa = (f32x4){0.f,0.f,0.f,0.f};
        sa = __builtin_amdgcn_mfma_f32_16x16x32_bf16(vb0, aq[qi][0], sa, 0,0,0);
        sa = __builtin_amdgcn_mfma_f32_16x16x32_bf16(vb1, aq[qi][1], sa, 0,0,0);
        float p0 = fast_exp2(fmaf(sa[0], C_QSCALE, mt0));
        float p1 = fast_exp2(fmaf(sa[1], C_QSCALE, mt1));
        float p2 = fast_exp2(fmaf(sa[2], C_QSCALE, mt2));
        float p3 = fast_exp2(fmaf(sa[3], C_QSCALE, mt3));
        X[qi][nt][0] = cvt_pk_bf16(p0, p1);
        X[qi][nt][1] = cvt_pk_bf16(p2, p3);
      }
    }
    // ---- lane-row exchange: X -> PV B-frags ----
    bf16x8 ap[2][2];
    #pragma unroll
    for (int qi = 0; qi < 2; ++qi) {
      #pragma unroll
      for (int h = 0; h < 2; ++h) {
        unsigned x0 = X[qi][2*h][0],   x1 = X[qi][2*h][1];
        unsigned x2 = X[qi][2*h+1][0], x3 = X[qi][2*h+1][1];
        pl32swap(x0, x2); pl16swap(x0, x2);     // x0=A0 (kv 8g+0,1) x2=A2 (kv 8g+4,5)
        pl32swap(x1, x3); pl16swap(x1, x3);     // x1=A1 (kv 8g+2,3) x3=A3 (kv 8g+6,7)
        union { u32x4 u; bf16x8 b; } cvt;
        cvt.u[0] = x0; cvt.u[1] = x1; cvt.u[2] = x2; cvt.u[3] = x3;
        ap[qi][h] = cvt.b;
        lac[qi] = __builtin_amdgcn_mfma_f32_16x16x32_bf16(ones, ap[qi][h], lac[qi], 0,0,0);
      }
    }
    // ---- O^T += K^T-frag * P (d-major out) ----
    #pragma unroll
    for (int dt = 0; dt < 4; ++dt) {
      int d = dt*16 + c;
      bf16x8 bk0 = *(const bf16x8*)(kvp + d*64 + ((g ^ (c & 7))*8));
      bf16x8 bk1 = *(const bf16x8*)(kvp + d*64 + (((4 + g) ^ (c & 7))*8));
      #pragma unroll
      for (int qi = 0; qi < 2; ++qi) {
        O[qi][dt] = __builtin_amdgcn_mfma_f32_16x16x32_bf16(bk0, ap[qi][0], O[qi][dt], 0,0,0);
        O[qi][dt] = __builtin_amdgcn_mfma_f32_16x16x32_bf16(bk1, ap[qi][1], O[qi][dt], 0,0,0);
      }
    }
  }
  u16* POp = (z == 0) ? PO0 : PO1;
  #pragma unroll
  for (int qi = 0; qi < 2; ++qi) {
    int q = q0 + qi*16 + c;
    size_t qrow = (size_t)bh * LL + q;
    if (g == 0) PL[(size_t)(z*32 + bh) * LL + q] = lac[qi][0];   // col-sums: rows equal
    #pragma unroll
    for (int dt = 0; dt < 4; ++dt) {
      u16x4 o;
      #pragma unroll
      for (int r = 0; r < 4; ++r) o[r] = f2bf(O[qi][dt][r]);
      *(u16x4*)(POp + qrow*HD + dt*16 + 4*g) = o;
    }
  }
}

// ---------------- residual + LayerNorm -> fp32 out ----------------
__global__ __launch_bounds__(256) void k_ln(const float* __restrict__ OF, const float* __restrict__ E,
                                            const float* __restrict__ gamma, const float* __restrict__ beta,
                                            float* __restrict__ out) {
  int row = blockIdx.x;
  int tid = threadIdx.x, lane = tid & 63, w = tid >> 6;
  size_t basei = (size_t)row * HH + tid*4;
  float4 a = *(const float4*)(OF + basei);
  float4 e = *(const float4*)(E + basei);
  float x0 = a.x + e.x, x1 = a.y + e.y, x2 = a.z + e.z, x3 = a.w + e.w;
  float s1 = x0+x1+x2+x3;
  float s2 = x0*x0+x1*x1+x2*x2+x3*x3;
  #pragma unroll
  for (int off = 32; off; off >>= 1) { s1 += __shfl_xor(s1, off); s2 += __shfl_xor(s2, off); }
  __shared__ float r1[4], r2[4];
  if (lane == 0) { r1[w] = s1; r2[w] = s2; }
  __syncthreads();
  s1 = r1[0]+r1[1]+r1[2]+r1[3];
  s2 = r2[0]+r2[1]+r2[2]+r2[3];
  float mu = s1 * (1.0f/HH);
  float var = s2 * (1.0f/HH) - mu*mu;
  float rs = rsqrtf(fmaxf(var, 0.f) + 1e-12f);
  int colb = tid*4;
  float4 gm = *(const float4*)(gamma + colb);
  float4 bt = *(const float4*)(beta + colb);
  float4 o;
  o.x = (x0-mu)*rs*gm.x + bt.x;
  o.y = (x1-mu)*rs*gm.y + bt.y;
  o.z = (x2-mu)*rs*gm.z + bt.z;
  o.w = (x3-mu)*rs*gm.w + bt.w;
  *(float4*)(out + basei) = o;
}

extern "C" void kernel_launch(void* const* d_in, const int* in_sizes, int n_in,
                              void* d_out, int out_size, void* d_ws, size_t ws_size,
                              hipStream_t stream) {
  const float* E    = (const float*)d_in[0];
  const float* mask = (const float*)d_in[1];
  const float* Wq   = (const float*)d_in[2];
  const float* bq   = (const float*)d_in[3];
  const float* Wk   = (const float*)d_in[4];
  const float* bk   = (const float*)d_in[5];
  const float* Wv   = (const float*)d_in[6];
  const float* bv   = (const float*)d_in[7];
  const float* Wo   = (const float*)d_in[8];
  const float* bo   = (const float*)d_in[9];
  const float* gam  = (const float*)d_in[10];
  const float* bet  = (const float*)d_in[11];

  const size_t MH = (size_t)ML * HH;      // 4M elems
  u16* XBF = (u16*)d_ws;                  // 8 MB bf16 embeddings (dead after QKV gemm)
  u16* WT  = XBF + MH;                    // 8 MB: Wq^T,Wk^T,Wv^T,Wo^T bf16 [n][k]
  u16* QH  = WT + 4*(size_t)HH*HH;        // 8 MB, [bh][l][d] (dead after k_attn)
  u16* KV  = QH + MH;                     // 16 MB (dead after k_attn)
  u16* PO0 = KV + 2*MH;                   // 8 MB partial O, key half 0 (live through k_gemm_o)
  u16* PO1 = PO0 + MH;                    // 8 MB partial O, key half 1 (live through k_gemm_o)
  float* out = (float*)d_out;
  float* PL = out;                        // 512 KB partial l in d_out (consumed by k_gemm_o; k_ln overwrites)
  float* OF = (float*)QH;                 // 16 MB fp32, overlays QH+KV (both dead after k_attn)

  k_prep<<<dim3(3072), 256, 0, stream>>>(E, XBF, Wq, Wk, Wv, Wo, WT);
  k_gemm<<<dim3(24,32), 256, 0, stream>>>(XBF, WT, bq, bk, bv, QH, KV);
  k_attn<<<dim3(16,2,32), 256, 0, stream>>>(QH, KV, mask, PO0, PO1, PL);
  k_gemm_o<<<dim3(8,64), 256, 0, stream>>>(PO0, PO1, PL, WT + 3*(size_t)HH*HH, bo, OF);
  k_ln<<<dim3(ML), 256, 0, stream>>>(OF, E, gam, bet, out);
}